// Round 1
// baseline (1145.693 us; speedup 1.0000x reference)
//
#include <hip/hip_runtime.h>

#define NN 50000
#define NE 800000
#define HD 256
#define BN_EPS 1e-5f

// ---------------- CSR build (dst-indexed) ----------------
__global__ __launch_bounds__(256) void k_count(const int* __restrict__ dst, int* __restrict__ cnt) {
  int e = blockIdx.x * 256 + threadIdx.x;
  if (e < NE) atomicAdd(&cnt[dst[e]], 1);
}

// single-block exclusive scan over NN counts; writes row_ptr and resets cursor to row start
__global__ __launch_bounds__(1024) void k_scan(int* __restrict__ cnt_cursor, int* __restrict__ rp) {
  __shared__ int sm[1024];
  __shared__ int carry;
  if (threadIdx.x == 0) carry = 0;
  __syncthreads();
  for (int base = 0; base < NN; base += 1024) {
    int i = base + threadIdx.x;
    int v = (i < NN) ? cnt_cursor[i] : 0;
    sm[threadIdx.x] = v;
    __syncthreads();
    for (int off = 1; off < 1024; off <<= 1) {
      int tv = (threadIdx.x >= off) ? sm[threadIdx.x - off] : 0;
      __syncthreads();
      sm[threadIdx.x] += tv;
      __syncthreads();
    }
    int incl = sm[threadIdx.x] + carry;
    if (i < NN) { rp[i] = incl - v; cnt_cursor[i] = incl - v; }
    __syncthreads();
    if (threadIdx.x == 1023) carry = incl;
    __syncthreads();
  }
  if (threadIdx.x == 0) rp[NN] = carry;
}

__global__ __launch_bounds__(256) void k_fill(const int* __restrict__ src, const int* __restrict__ dst,
                                              int* __restrict__ cursor, int* __restrict__ col) {
  int e = blockIdx.x * 256 + threadIdx.x;
  if (e < NE) {
    int p = atomicAdd(&cursor[dst[e]], 1);
    col[p] = src[e];
  }
}

// ---------------- layer 1: aggregate x (F=9), u stored [NN,16] ----------------
__global__ __launch_bounds__(256) void k_agg9(const float* __restrict__ x,
    const int* __restrict__ rp, const int* __restrict__ col, float* __restrict__ u) {
  int i = blockIdx.x * 256 + threadIdx.x;
  if (i >= NN) return;
  float a[9];
  #pragma unroll
  for (int k = 0; k < 9; ++k) a[k] = x[(size_t)i * 9 + k];
  int e1 = rp[i + 1];
  for (int e = rp[i]; e < e1; ++e) {
    int nb = col[e];
    #pragma unroll
    for (int k = 0; k < 9; ++k) a[k] += x[(size_t)nb * 9 + k];
  }
  #pragma unroll
  for (int k = 0; k < 9; ++k) u[(size_t)i * 16 + k] = a[k];
}

// ---------------- layer 1 GEMM: h = u[N,9] @ W1[9,256] + b1, + column stats ----------------
__global__ __launch_bounds__(256) void k_l1gemm(const float* __restrict__ u,
    const float* __restrict__ W1, const float* __restrict__ b1,
    float* __restrict__ h, float* __restrict__ s_sum, float* __restrict__ s_sq) {
  __shared__ float Ws[9][256];
  int t = threadIdx.x;
  #pragma unroll
  for (int k = 0; k < 9; ++k) Ws[k][t] = W1[k * 256 + t];
  float bj = b1[t];
  __syncthreads();
  int r0 = blockIdx.x * 128;
  int r1 = min(r0 + 128, NN);
  float sum = 0.f, sq = 0.f;
  for (int r = r0; r < r1; ++r) {
    float acc = bj;
    #pragma unroll
    for (int k = 0; k < 9; ++k) acc = fmaf(u[(size_t)r * 16 + k], Ws[k][t], acc);
    h[(size_t)r * 256 + t] = acc;
    sum += acc; sq += acc * acc;
  }
  atomicAdd(&s_sum[t], sum);
  atomicAdd(&s_sq[t], sq);
}

// ---------------- BN finalize ----------------
__global__ void k_finalize(const float* __restrict__ s_sum, const float* __restrict__ s_sq,
                           float* __restrict__ meanb, float* __restrict__ rstdb) {
  int j = threadIdx.x;
  float m = s_sum[j] / (float)NN;
  float v = s_sq[j] / (float)NN - m * m;
  v = fmaxf(v, 0.f);
  meanb[j] = m;
  rstdb[j] = rsqrtf(v + BN_EPS);
}

// ---------------- aggregation F=256: u = f[i] + sum_nb f[nb] ----------------
__global__ __launch_bounds__(256) void k_agg256(const float* __restrict__ f,
    const int* __restrict__ rp, const int* __restrict__ col, float* __restrict__ u) {
  int node = blockIdx.x * 4 + threadIdx.y;
  if (node >= NN) return;
  int lane = threadIdx.x;
  float4 acc = *(const float4*)(f + (size_t)node * HD + lane * 4);
  int e0 = rp[node], e1 = rp[node + 1];
  for (int e = e0; e < e1; ++e) {
    int nb = col[e];
    float4 v = *(const float4*)(f + (size_t)nb * HD + lane * 4);
    acc.x += v.x; acc.y += v.y; acc.z += v.z; acc.w += v.w;
  }
  *(float4*)(u + (size_t)node * HD + lane * 4) = acc;
}

// ---------------- tiled fp32 GEMM with fused pre/post ops ----------------
// C[N,256] = op(A)[N,256] @ B[256,256] + bias
// PRE_BN:   a = relu((A - mean) * rstd * gamma + beta) applied while staging A
// POST_STATS: atomically accumulate column sum & sumsq of C (pre-relu output)
// POST_RELU: relu on output
// OUT_SUM:  atomically accumulate column sums of output into out[256]
// WRITE_C:  write C
template<bool PRE_BN, bool POST_STATS, bool POST_RELU, bool OUT_SUM, bool WRITE_C>
__global__ __launch_bounds__(256) void k_gemm(
    const float* __restrict__ A, const float* __restrict__ B, const float* __restrict__ bias,
    const float* __restrict__ mean, const float* __restrict__ rstd,
    const float* __restrict__ gamma, const float* __restrict__ beta,
    float* __restrict__ C, float* __restrict__ s_sum, float* __restrict__ s_sq,
    float* __restrict__ out)
{
  __shared__ float As[16][64];  // [k][m]
  __shared__ float Bs[16][64];  // [k][n]
  const int t = threadIdx.x;
  const int row0 = blockIdx.x * 64;
  const int col0 = blockIdx.y * 64;
  const int tm = t & 15, tn = t >> 4;
  const int m0 = tm * 4, n0 = tn * 4;
  float c[4][4] = {};
  for (int kt = 0; kt < HD; kt += 16) {
    #pragma unroll
    for (int i = 0; i < 4; ++i) {
      int l = t + i * 256;
      int m = l >> 4, k = l & 15;
      int gr = row0 + m;
      float v = 0.f;
      if (gr < NN) v = A[(size_t)gr * HD + kt + k];
      if (PRE_BN) {
        int gk = kt + k;
        v = fmaf((v - mean[gk]) * rstd[gk], gamma[gk], beta[gk]);
        v = fmaxf(v, 0.f);
        if (gr >= NN) v = 0.f;  // padded rows must contribute zero
      }
      As[k][m] = v;
    }
    #pragma unroll
    for (int i = 0; i < 4; ++i) {
      int l = t + i * 256;
      int r = l >> 6, cc = l & 63;
      Bs[r][cc] = B[(size_t)(kt + r) * HD + col0 + cc];
    }
    __syncthreads();
    #pragma unroll
    for (int k = 0; k < 16; ++k) {
      float4 a4 = *(const float4*)&As[k][m0];
      float4 b4 = *(const float4*)&Bs[k][n0];
      float a[4] = {a4.x, a4.y, a4.z, a4.w};
      float b[4] = {b4.x, b4.y, b4.z, b4.w};
      #pragma unroll
      for (int i = 0; i < 4; ++i)
        #pragma unroll
        for (int j = 0; j < 4; ++j)
          c[i][j] = fmaf(a[i], b[j], c[i][j]);
    }
    __syncthreads();
  }
  float bv[4];
  #pragma unroll
  for (int j = 0; j < 4; ++j) bv[j] = bias[col0 + n0 + j];
  float vals[4][4];
  #pragma unroll
  for (int i = 0; i < 4; ++i)
    #pragma unroll
    for (int j = 0; j < 4; ++j) {
      float v = c[i][j] + bv[j];
      if (POST_RELU) v = fmaxf(v, 0.f);
      vals[i][j] = v;
    }
  if (WRITE_C) {
    #pragma unroll
    for (int i = 0; i < 4; ++i) {
      int gr = row0 + m0 + i;
      if (gr < NN)
        *(float4*)&C[(size_t)gr * HD + col0 + n0] =
            make_float4(vals[i][0], vals[i][1], vals[i][2], vals[i][3]);
    }
  }
  if (POST_STATS || OUT_SUM) {
    float ps[4] = {0.f, 0.f, 0.f, 0.f}, pq[4] = {0.f, 0.f, 0.f, 0.f};
    #pragma unroll
    for (int i = 0; i < 4; ++i) {
      int gr = row0 + m0 + i;
      if (gr < NN) {
        #pragma unroll
        for (int j = 0; j < 4; ++j) {
          ps[j] += vals[i][j];
          if (POST_STATS) pq[j] += vals[i][j] * vals[i][j];
        }
      }
    }
    #pragma unroll
    for (int j = 0; j < 4; ++j) {
      As[tm][n0 + j] = ps[j];
      if (POST_STATS) Bs[tm][n0 + j] = pq[j];
    }
    __syncthreads();
    if (t < 64) {
      float s = 0.f, q = 0.f;
      #pragma unroll
      for (int g = 0; g < 16; ++g) {
        s += As[g][t];
        if (POST_STATS) q += Bs[g][t];
      }
      if (POST_STATS) { atomicAdd(&s_sum[col0 + t], s); atomicAdd(&s_sq[col0 + t], q); }
      if (OUT_SUM) atomicAdd(&out[col0 + t], s);
    }
  }
}

extern "C" void kernel_launch(void* const* d_in, const int* in_sizes, int n_in,
                              void* d_out, int out_size, void* d_ws, size_t ws_size,
                              hipStream_t stream) {
  (void)in_sizes; (void)n_in; (void)out_size; (void)ws_size;
  const float* x  = (const float*)d_in[0];
  const int*  ei  = (const int*)d_in[1];   // JAX x64 disabled -> int32
  const int*  src = ei;
  const int*  dst = ei + NE;
  const float* W1[3] = {(const float*)d_in[2],  (const float*)d_in[8],  (const float*)d_in[14]};
  const float* b1[3] = {(const float*)d_in[3],  (const float*)d_in[9],  (const float*)d_in[15]};
  const float* g_[3] = {(const float*)d_in[4],  (const float*)d_in[10], (const float*)d_in[16]};
  const float* be[3] = {(const float*)d_in[5],  (const float*)d_in[11], (const float*)d_in[17]};
  const float* W2[3] = {(const float*)d_in[6],  (const float*)d_in[12], (const float*)d_in[18]};
  const float* b2[3] = {(const float*)d_in[7],  (const float*)d_in[13], (const float*)d_in[19]};

  char* ws = (char*)d_ws;
  size_t o = 0;
  auto alloc = [&](size_t bytes) -> void* {
    void* p = ws + o;
    o += (bytes + 255) & ~(size_t)255;
    return p;
  };
  int*   rp     = (int*)alloc((size_t)(NN + 1) * 4);
  int*   cursor = (int*)alloc((size_t)NN * 4);
  int*   col    = (int*)alloc((size_t)NE * 4);
  float* u      = (float*)alloc((size_t)NN * HD * 4);
  float* h      = (float*)alloc((size_t)NN * HD * 4);
  float* f      = (float*)alloc((size_t)NN * HD * 4);
  float* s_sum  = (float*)alloc(HD * 4);
  float* s_sq   = (float*)alloc(HD * 4);
  float* meanb  = (float*)alloc(HD * 4);
  float* rstdb  = (float*)alloc(HD * 4);
  float* out    = (float*)d_out;

  hipMemsetAsync(cursor, 0, (size_t)NN * 4, stream);
  hipMemsetAsync(out, 0, HD * 4, stream);
  k_count<<<(NE + 255) / 256, 256, 0, stream>>>(dst, cursor);
  k_scan<<<1, 1024, 0, stream>>>(cursor, rp);
  k_fill<<<(NE + 255) / 256, 256, 0, stream>>>(src, dst, cursor, col);

  dim3 gGrid((NN + 63) / 64, HD / 64);
  dim3 aGrid((NN + 3) / 4);
  dim3 aBlk(64, 4);

  // ---- layer 1 ----
  hipMemsetAsync(s_sum, 0, HD * 4, stream);
  hipMemsetAsync(s_sq, 0, HD * 4, stream);
  k_agg9<<<(NN + 255) / 256, 256, 0, stream>>>(x, rp, col, u);
  k_l1gemm<<<(NN + 127) / 128, 256, 0, stream>>>(u, W1[0], b1[0], h, s_sum, s_sq);
  k_finalize<<<1, HD, 0, stream>>>(s_sum, s_sq, meanb, rstdb);
  k_gemm<true, false, true, false, true><<<gGrid, 256, 0, stream>>>(
      h, W2[0], b2[0], meanb, rstdb, g_[0], be[0], f, nullptr, nullptr, nullptr);

  // ---- layers 2 & 3 ----
  for (int L = 1; L < 3; ++L) {
    hipMemsetAsync(s_sum, 0, HD * 4, stream);
    hipMemsetAsync(s_sq, 0, HD * 4, stream);
    k_agg256<<<aGrid, aBlk, 0, stream>>>(f, rp, col, u);
    k_gemm<false, true, false, false, true><<<gGrid, 256, 0, stream>>>(
        u, W1[L], b1[L], nullptr, nullptr, nullptr, nullptr, h, s_sum, s_sq, nullptr);
    k_finalize<<<1, HD, 0, stream>>>(s_sum, s_sq, meanb, rstdb);
    if (L == 2) {
      k_gemm<true, false, true, true, false><<<gGrid, 256, 0, stream>>>(
          h, W2[L], b2[L], meanb, rstdb, g_[L], be[L], nullptr, nullptr, nullptr, out);
    } else {
      k_gemm<true, false, true, false, true><<<gGrid, 256, 0, stream>>>(
          h, W2[L], b2[L], meanb, rstdb, g_[L], be[L], f, nullptr, nullptr, nullptr);
    }
  }
}

// Round 2
// 606.123 us; speedup vs baseline: 1.8902x; 1.8902x over previous
//
#include <hip/hip_runtime.h>

#define NN 50000
#define NE 800000
#define HD 256
#define BN_EPS 1e-5f

typedef __attribute__((ext_vector_type(8))) short bf16x8;
typedef __attribute__((ext_vector_type(8))) unsigned short ushort8;
typedef __attribute__((ext_vector_type(4))) float f32x4;

__device__ __forceinline__ float bf2f(unsigned short u) {
  union { unsigned int i; float f; } c; c.i = ((unsigned int)u) << 16; return c.f;
}
__device__ __forceinline__ unsigned short f2bf(float x) {
  union { float f; unsigned int i; } c; c.f = x;
  unsigned int r = (c.i + 0x7fffu + ((c.i >> 16) & 1u)) >> 16;
  return (unsigned short)r;
}

// ---------------- CSR build (dst-indexed) ----------------
__global__ __launch_bounds__(256) void k_count(const int* __restrict__ dst, int* __restrict__ cnt) {
  int e = blockIdx.x * 256 + threadIdx.x;
  if (e < NE) atomicAdd(&cnt[dst[e]], 1);
}

__global__ __launch_bounds__(1024) void k_scan(int* __restrict__ cnt_cursor, int* __restrict__ rp) {
  __shared__ int sm[1024];
  __shared__ int carry;
  if (threadIdx.x == 0) carry = 0;
  __syncthreads();
  for (int base = 0; base < NN; base += 1024) {
    int i = base + threadIdx.x;
    int v = (i < NN) ? cnt_cursor[i] : 0;
    sm[threadIdx.x] = v;
    __syncthreads();
    for (int off = 1; off < 1024; off <<= 1) {
      int tv = (threadIdx.x >= off) ? sm[threadIdx.x - off] : 0;
      __syncthreads();
      sm[threadIdx.x] += tv;
      __syncthreads();
    }
    int incl = sm[threadIdx.x] + carry;
    if (i < NN) { rp[i] = incl - v; cnt_cursor[i] = incl - v; }
    __syncthreads();
    if (threadIdx.x == 1023) carry = incl;
    __syncthreads();
  }
  if (threadIdx.x == 0) rp[NN] = carry;
}

__global__ __launch_bounds__(256) void k_fill(const int* __restrict__ src, const int* __restrict__ dst,
                                              int* __restrict__ cursor, int* __restrict__ col) {
  int e = blockIdx.x * 256 + threadIdx.x;
  if (e < NE) {
    int p = atomicAdd(&cursor[dst[e]], 1);
    col[p] = src[e];
  }
}

// ---------------- weight prep: fp32 [256][256] -> bf16 MFMA-fragment layout ----------------
// fragment coords for mfma_f32_16x16x32_bf16 B-operand:
//   nt=n>>4, ks=k>>5, lane=((k>>3)&3)*16+(n&15), j=k&7
__global__ __launch_bounds__(256) void k_prepW(const float* __restrict__ W, unsigned short* __restrict__ out) {
  int k = blockIdx.x, n = threadIdx.x;
  int nt = n >> 4, ks = k >> 5, lane = ((k >> 3) & 3) * 16 + (n & 15), j = k & 7;
  out[(size_t)((nt * 8 + ks) * 64 + lane) * 8 + j] = f2bf(W[k * 256 + n]);
}

// ---------------- layer 1: aggregate x (F=9), u stored [NN,16] fp32 ----------------
__global__ __launch_bounds__(256) void k_agg9(const float* __restrict__ x,
    const int* __restrict__ rp, const int* __restrict__ col, float* __restrict__ u) {
  int i = blockIdx.x * 256 + threadIdx.x;
  if (i >= NN) return;
  float a[9];
  #pragma unroll
  for (int k = 0; k < 9; ++k) a[k] = x[(size_t)i * 9 + k];
  int e1 = rp[i + 1];
  for (int e = rp[i]; e < e1; ++e) {
    int nb = col[e];
    #pragma unroll
    for (int k = 0; k < 9; ++k) a[k] += x[(size_t)nb * 9 + k];
  }
  #pragma unroll
  for (int k = 0; k < 9; ++k) u[(size_t)i * 16 + k] = a[k];
}

// ---------------- layer 1 GEMM (K=9, fp32): h(bf16) = u @ W1 + b1, + column stats ----------------
__global__ __launch_bounds__(256) void k_l1gemm(const float* __restrict__ u,
    const float* __restrict__ W1, const float* __restrict__ b1,
    unsigned short* __restrict__ h, float* __restrict__ s_sum, float* __restrict__ s_sq) {
  __shared__ float Ws[9][256];
  int t = threadIdx.x;
  #pragma unroll
  for (int k = 0; k < 9; ++k) Ws[k][t] = W1[k * 256 + t];
  float bj = b1[t];
  __syncthreads();
  int r0 = blockIdx.x * 128;
  int r1 = min(r0 + 128, NN);
  float sum = 0.f, sq = 0.f;
  for (int r = r0; r < r1; ++r) {
    float acc = bj;
    #pragma unroll
    for (int k = 0; k < 9; ++k) acc = fmaf(u[(size_t)r * 16 + k], Ws[k][t], acc);
    h[(size_t)r * 256 + t] = f2bf(acc);
    sum += acc; sq += acc * acc;
  }
  atomicAdd(&s_sum[t], sum);
  atomicAdd(&s_sq[t], sq);
}

// ---------------- BN finalize: scale = rstd*gamma, shift = beta - mean*scale ----------------
__global__ void k_finalize(const float* __restrict__ s_sum, const float* __restrict__ s_sq,
                           const float* __restrict__ g, const float* __restrict__ be,
                           float* __restrict__ scale, float* __restrict__ shift) {
  int j = threadIdx.x;
  float m = s_sum[j] / (float)NN;
  float v = s_sq[j] / (float)NN - m * m;
  v = fmaxf(v, 0.f);
  float rs = rsqrtf(v + BN_EPS);
  float sc = rs * g[j];
  scale[j] = sc;
  shift[j] = be[j] - m * sc;
}

// ---------------- BN apply + relu, bf16 -> bf16 ----------------
__global__ __launch_bounds__(256) void k_bnapply(const unsigned short* __restrict__ h,
    const float* __restrict__ scale, const float* __restrict__ shift, unsigned short* __restrict__ a) {
  __shared__ float sc[256], sh[256];
  sc[threadIdx.x] = scale[threadIdx.x];
  sh[threadIdx.x] = shift[threadIdx.x];
  __syncthreads();
  const int total = NN * 32;  // chunks of 8 bf16
  for (int idx = blockIdx.x * 256 + threadIdx.x; idx < total; idx += gridDim.x * 256) {
    int c0 = (idx & 31) * 8;
    ushort8 v = *(const ushort8*)(h + (size_t)idx * 8);
    ushort8 o;
    #pragma unroll
    for (int j = 0; j < 8; ++j) {
      float f = bf2f(v[j]);
      f = fmaxf(fmaf(f, sc[c0 + j], sh[c0 + j]), 0.f);
      o[j] = f2bf(f);
    }
    *(ushort8*)(a + (size_t)idx * 8) = o;
  }
}

// ---------------- aggregation F=256 bf16: u = f[i] + sum_nb f[nb] ----------------
__global__ __launch_bounds__(256) void k_agg256(const unsigned short* __restrict__ f,
    const int* __restrict__ rp, const int* __restrict__ col, unsigned short* __restrict__ u) {
  int half = threadIdx.x >> 5;
  int lane32 = threadIdx.x & 31;
  int node = blockIdx.x * 8 + threadIdx.y * 2 + half;
  if (node >= NN) return;
  float acc[8];
  ushort8 v = *(const ushort8*)(f + (size_t)node * HD + lane32 * 8);
  #pragma unroll
  for (int j = 0; j < 8; ++j) acc[j] = bf2f(v[j]);
  int e0 = rp[node], e1 = rp[node + 1];
  for (int e = e0; e < e1; ++e) {
    int nb = col[e];
    ushort8 w = *(const ushort8*)(f + (size_t)nb * HD + lane32 * 8);
    #pragma unroll
    for (int j = 0; j < 8; ++j) acc[j] += bf2f(w[j]);
  }
  ushort8 o;
  #pragma unroll
  for (int j = 0; j < 8; ++j) o[j] = f2bf(acc[j]);
  *(ushort8*)(u + (size_t)node * HD + lane32 * 8) = o;
}

// ---------------- MFMA bf16 GEMM: C[NN,256] = A[NN,256] @ B[256,256] + bias ----------------
// 64-row blocks, 4 waves each own a 64-col quadrant; B in registers (prep layout);
// A double-buffered in LDS via global_load_lds, XOR granule swizzle (g' = g ^ (row&7)).
template<bool STATS, bool RELU, bool OUTSUM, bool WRITE>
__global__ __launch_bounds__(256, 2) void k_mfma_gemm(
    const unsigned short* __restrict__ A, const unsigned short* __restrict__ Bp,
    const float* __restrict__ bias, unsigned short* __restrict__ C,
    float* __restrict__ s_sum, float* __restrict__ s_sq, float* __restrict__ out)
{
  __shared__ unsigned short As[2][64 * 64];  // 16 KB
  const int t = threadIdx.x;
  const int w = t >> 6;
  const int lane = t & 63;
  const int brow = blockIdx.x * 64;

  // B fragments: wave w covers cols [w*64, w*64+64)
  bf16x8 bfr[4][8];
  #pragma unroll
  for (int ntl = 0; ntl < 4; ++ntl)
    #pragma unroll
    for (int ks = 0; ks < 8; ++ks) {
      int ntg = w * 4 + ntl;
      bfr[ntl][ks] = *(const bf16x8*)(Bp + (size_t)((ntg * 8 + ks) * 64 + lane) * 8);
    }

  f32x4 zero; zero.x = zero.y = zero.z = zero.w = 0.f;
  f32x4 acc[4][4];
  #pragma unroll
  for (int i = 0; i < 4; ++i)
    #pragma unroll
    for (int j = 0; j < 4; ++j) acc[i][j] = zero;

  auto stage = [&](int buf, int kt) {
    #pragma unroll
    for (int hh = 0; hh < 2; ++hh) {
      int r0 = w * 16 + hh * 8;
      int row = r0 + (lane >> 3);
      int gp = (lane & 7) ^ (row & 7);          // inverse-swizzled source granule
      int grow = brow + row; if (grow >= NN) grow = NN - 1;
      const unsigned short* gptr = A + (size_t)grow * HD + kt + gp * 8;
      __builtin_amdgcn_global_load_lds(
          (const __attribute__((address_space(1))) void*)gptr,
          (__attribute__((address_space(3))) void*)&As[buf][r0 * 64], 16, 0, 0);
    }
  };

  stage(0, 0);
  __syncthreads();

  #pragma unroll
  for (int tt = 0; tt < 4; ++tt) {
    if (tt < 3) stage((tt + 1) & 1, (tt + 1) * 64);
    const int buf = tt & 1;
    #pragma unroll
    for (int s = 0; s < 2; ++s) {
      bf16x8 afr[4];
      #pragma unroll
      for (int mt = 0; mt < 4; ++mt) {
        int row = mt * 16 + (lane & 15);
        int g = s * 4 + (lane >> 4);
        int gp = g ^ (row & 7);
        afr[mt] = *(const bf16x8*)&As[buf][row * 64 + gp * 8];
      }
      #pragma unroll
      for (int mt = 0; mt < 4; ++mt)
        #pragma unroll
        for (int ntl = 0; ntl < 4; ++ntl)
          acc[mt][ntl] = __builtin_amdgcn_mfma_f32_16x16x32_bf16(
              afr[mt], bfr[ntl][tt * 2 + s], acc[mt][ntl], 0, 0, 0);
    }
    __syncthreads();
  }

  // epilogue
  const int cl = lane & 15;
  const int rq = (lane >> 4) * 4;
  #pragma unroll
  for (int ntl = 0; ntl < 4; ++ntl) {
    const int cgl = w * 64 + ntl * 16 + cl;
    const float bv = bias[cgl];
    float s = 0.f, q = 0.f;
    #pragma unroll
    for (int mt = 0; mt < 4; ++mt) {
      #pragma unroll
      for (int i = 0; i < 4; ++i) {
        float v = acc[mt][ntl][i] + bv;
        if (RELU) v = fmaxf(v, 0.f);
        int grow = brow + mt * 16 + rq + i;
        bool valid = grow < NN;
        if (WRITE && valid) C[(size_t)grow * HD + cgl] = f2bf(v);
        if ((STATS || OUTSUM) && valid) { s += v; if (STATS) q += v * v; }
      }
    }
    if (STATS || OUTSUM) {
      s += __shfl_xor(s, 16); s += __shfl_xor(s, 32);
      if (STATS) { q += __shfl_xor(q, 16); q += __shfl_xor(q, 32); }
      if (lane < 16) {
        if (STATS) { atomicAdd(&s_sum[cgl], s); atomicAdd(&s_sq[cgl], q); }
        if (OUTSUM) atomicAdd(&out[cgl], s);
      }
    }
  }
}

extern "C" void kernel_launch(void* const* d_in, const int* in_sizes, int n_in,
                              void* d_out, int out_size, void* d_ws, size_t ws_size,
                              hipStream_t stream) {
  (void)in_sizes; (void)n_in; (void)out_size; (void)ws_size;
  const float* x  = (const float*)d_in[0];
  const int*  ei  = (const int*)d_in[1];
  const int*  src = ei;
  const int*  dst = ei + NE;
  const float* W1[3] = {(const float*)d_in[2],  (const float*)d_in[8],  (const float*)d_in[14]};
  const float* b1[3] = {(const float*)d_in[3],  (const float*)d_in[9],  (const float*)d_in[15]};
  const float* g_[3] = {(const float*)d_in[4],  (const float*)d_in[10], (const float*)d_in[16]};
  const float* be[3] = {(const float*)d_in[5],  (const float*)d_in[11], (const float*)d_in[17]};
  const float* W2[3] = {(const float*)d_in[6],  (const float*)d_in[12], (const float*)d_in[18]};
  const float* b2[3] = {(const float*)d_in[7],  (const float*)d_in[13], (const float*)d_in[19]};

  char* ws = (char*)d_ws;
  size_t o = 0;
  auto alloc = [&](size_t bytes) -> void* {
    void* p = ws + o;
    o += (bytes + 255) & ~(size_t)255;
    return p;
  };
  int*   rp     = (int*)alloc((size_t)(NN + 1) * 4);
  int*   cursor = (int*)alloc((size_t)NN * 4);
  int*   col    = (int*)alloc((size_t)NE * 4);
  float* u9     = (float*)alloc((size_t)NN * 16 * 4);
  unsigned short* ubf = (unsigned short*)alloc((size_t)NN * HD * 2);
  unsigned short* hbf = (unsigned short*)alloc((size_t)NN * HD * 2);
  unsigned short* abf = (unsigned short*)alloc((size_t)NN * HD * 2);
  unsigned short* fbf = (unsigned short*)alloc((size_t)NN * HD * 2);
  unsigned short* Wp[5];
  for (int i = 0; i < 5; ++i) Wp[i] = (unsigned short*)alloc((size_t)HD * HD * 2);
  float* s_sum  = (float*)alloc(HD * 4);
  float* s_sq   = (float*)alloc(HD * 4);
  float* scale  = (float*)alloc(HD * 4);
  float* shift  = (float*)alloc(HD * 4);
  float* out    = (float*)d_out;

  hipMemsetAsync(cursor, 0, (size_t)NN * 4, stream);
  hipMemsetAsync(out, 0, HD * 4, stream);
  k_count<<<(NE + 255) / 256, 256, 0, stream>>>(dst, cursor);
  k_scan<<<1, 1024, 0, stream>>>(cursor, rp);
  k_fill<<<(NE + 255) / 256, 256, 0, stream>>>(src, dst, cursor, col);

  k_prepW<<<256, 256, 0, stream>>>(W2[0], Wp[0]);
  k_prepW<<<256, 256, 0, stream>>>(W1[1], Wp[1]);
  k_prepW<<<256, 256, 0, stream>>>(W2[1], Wp[2]);
  k_prepW<<<256, 256, 0, stream>>>(W1[2], Wp[3]);
  k_prepW<<<256, 256, 0, stream>>>(W2[2], Wp[4]);

  const int gemmGrid = (NN + 63) / 64;
  dim3 aGrid((NN + 7) / 8);
  dim3 aBlk(64, 4);

  // ---- layer 1 ----
  hipMemsetAsync(s_sum, 0, HD * 4, stream);
  hipMemsetAsync(s_sq, 0, HD * 4, stream);
  k_agg9<<<(NN + 255) / 256, 256, 0, stream>>>(x, rp, col, u9);
  k_l1gemm<<<(NN + 127) / 128, 256, 0, stream>>>(u9, W1[0], b1[0], hbf, s_sum, s_sq);
  k_finalize<<<1, HD, 0, stream>>>(s_sum, s_sq, g_[0], be[0], scale, shift);
  k_bnapply<<<2048, 256, 0, stream>>>(hbf, scale, shift, abf);
  k_mfma_gemm<false, true, false, true><<<gemmGrid, 256, 0, stream>>>(
      abf, Wp[0], b2[0], fbf, nullptr, nullptr, nullptr);

  // ---- layer 2 ----
  hipMemsetAsync(s_sum, 0, HD * 4, stream);
  hipMemsetAsync(s_sq, 0, HD * 4, stream);
  k_agg256<<<aGrid, aBlk, 0, stream>>>(fbf, rp, col, ubf);
  k_mfma_gemm<true, false, false, true><<<gemmGrid, 256, 0, stream>>>(
      ubf, Wp[1], b1[1], hbf, s_sum, s_sq, nullptr);
  k_finalize<<<1, HD, 0, stream>>>(s_sum, s_sq, g_[1], be[1], scale, shift);
  k_bnapply<<<2048, 256, 0, stream>>>(hbf, scale, shift, abf);
  k_mfma_gemm<false, true, false, true><<<gemmGrid, 256, 0, stream>>>(
      abf, Wp[2], b2[1], fbf, nullptr, nullptr, nullptr);

  // ---- layer 3 ----
  hipMemsetAsync(s_sum, 0, HD * 4, stream);
  hipMemsetAsync(s_sq, 0, HD * 4, stream);
  k_agg256<<<aGrid, aBlk, 0, stream>>>(fbf, rp, col, ubf);
  k_mfma_gemm<true, false, false, true><<<gemmGrid, 256, 0, stream>>>(
      ubf, Wp[3], b1[2], hbf, s_sum, s_sq, nullptr);
  k_finalize<<<1, HD, 0, stream>>>(s_sum, s_sq, g_[2], be[2], scale, shift);
  k_bnapply<<<2048, 256, 0, stream>>>(hbf, scale, shift, abf);
  k_mfma_gemm<false, true, true, false><<<gemmGrid, 256, 0, stream>>>(
      abf, Wp[4], b2[2], nullptr, nullptr, nullptr, out);
}

// Round 3
// 469.020 us; speedup vs baseline: 2.4427x; 1.2923x over previous
//
#include <hip/hip_runtime.h>

#define NN 50000
#define NE 800000
#define HD 256
#define BN_EPS 1e-5f

typedef __attribute__((ext_vector_type(8))) short bf16x8;
typedef __attribute__((ext_vector_type(8))) unsigned short ushort8;
typedef __attribute__((ext_vector_type(4))) float f32x4;

__device__ __forceinline__ float bf2f(unsigned short u) {
  union { unsigned int i; float f; } c; c.i = ((unsigned int)u) << 16; return c.f;
}
__device__ __forceinline__ unsigned short f2bf(float x) {
  union { float f; unsigned int i; } c; c.f = x;
  unsigned int r = (c.i + 0x7fffu + ((c.i >> 16) & 1u)) >> 16;
  return (unsigned short)r;
}

// ---------------- zero scratch (one dispatch replaces all memsets) ----------------
__global__ __launch_bounds__(1024) void k_zero(int* __restrict__ cursor, float* __restrict__ s_sum,
                                               float* __restrict__ s_sq, float* __restrict__ out) {
  int i = blockIdx.x * 1024 + threadIdx.x;
  if (i < NN) cursor[i] = 0;
  if (i < HD) { s_sum[i] = 0.f; s_sq[i] = 0.f; out[i] = 0.f; }
}

// ---------------- CSR build (dst-indexed) ----------------
__global__ __launch_bounds__(256) void k_count(const int* __restrict__ dst, int* __restrict__ cnt) {
  int e = blockIdx.x * 256 + threadIdx.x;
  if (e < NE) atomicAdd(&cnt[dst[e]], 1);
}

// multi-block scan, stage A: per-block local exclusive scan into rp, block sums into bsum
__global__ __launch_bounds__(1024) void k_scan_a(const int* __restrict__ cnt,
                                                 int* __restrict__ rp, int* __restrict__ bsum) {
  __shared__ int wsum[16];
  int i = blockIdx.x * 1024 + threadIdx.x;
  int v = (i < NN) ? cnt[i] : 0;
  int lane = threadIdx.x & 63, wid = threadIdx.x >> 6;
  int s = v;
  #pragma unroll
  for (int off = 1; off < 64; off <<= 1) {
    int tv = __shfl_up(s, off);
    if (lane >= off) s += tv;
  }
  if (lane == 63) wsum[wid] = s;
  __syncthreads();
  if (wid == 0) {
    int ws = (lane < 16) ? wsum[lane] : 0;
    #pragma unroll
    for (int off = 1; off < 16; off <<= 1) {
      int tv = __shfl_up(ws, off);
      if (lane >= off) ws += tv;
    }
    if (lane < 16) wsum[lane] = ws;  // inclusive wave-sum scan
  }
  __syncthreads();
  int excl = s - v + (wid > 0 ? wsum[wid - 1] : 0);
  if (i < NN) rp[i] = excl;
  if (threadIdx.x == 1023) bsum[blockIdx.x] = excl + v;
}

// stage B: add block offsets; write cursor; rp[NN] = NE
__global__ __launch_bounds__(1024) void k_scan_b(const int* __restrict__ bsum,
                                                 int* __restrict__ rp, int* __restrict__ cursor) {
  __shared__ int off_s;
  if (threadIdx.x < 64) {
    int v = ((int)threadIdx.x < (int)blockIdx.x && threadIdx.x < 49) ? bsum[threadIdx.x] : 0;
    #pragma unroll
    for (int o = 32; o > 0; o >>= 1) v += __shfl_xor(v, o);
    if (threadIdx.x == 0) off_s = v;
  }
  __syncthreads();
  int i = blockIdx.x * 1024 + threadIdx.x;
  if (i < NN) {
    int r = rp[i] + off_s;
    rp[i] = r;
    cursor[i] = r;
  }
  if (blockIdx.x == 0 && threadIdx.x == 0) rp[NN] = NE;
}

__global__ __launch_bounds__(256) void k_fill(const int* __restrict__ src, const int* __restrict__ dst,
                                              int* __restrict__ cursor, int* __restrict__ col) {
  int e = blockIdx.x * 256 + threadIdx.x;
  if (e < NE) {
    int p = atomicAdd(&cursor[dst[e]], 1);
    col[p] = src[e];
  }
}

// ---------------- weight prep: 5 matrices fp32 [256][256] -> bf16 MFMA B-fragment layout ----------------
__global__ __launch_bounds__(256) void k_prepW5(const float* __restrict__ Wa, const float* __restrict__ Wb,
    const float* __restrict__ Wc, const float* __restrict__ Wd, const float* __restrict__ We,
    unsigned short* __restrict__ out) {
  const float* W = (blockIdx.y == 0) ? Wa : (blockIdx.y == 1) ? Wb : (blockIdx.y == 2) ? Wc
                   : (blockIdx.y == 3) ? Wd : We;
  unsigned short* O = out + (size_t)blockIdx.y * HD * HD;
  int k = blockIdx.x, n = threadIdx.x;
  int nt = n >> 4, ks = k >> 5, lane = ((k >> 3) & 3) * 16 + (n & 15), j = k & 7;
  O[(size_t)((nt * 8 + ks) * 64 + lane) * 8 + j] = f2bf(W[k * 256 + n]);
}

// ---------------- layer 1: aggregate x (F=9), u stored [NN,16] fp32 ----------------
__global__ __launch_bounds__(256) void k_agg9(const float* __restrict__ x,
    const int* __restrict__ rp, const int* __restrict__ col, float* __restrict__ u) {
  int i = blockIdx.x * 256 + threadIdx.x;
  if (i >= NN) return;
  float a[9];
  #pragma unroll
  for (int k = 0; k < 9; ++k) a[k] = x[(size_t)i * 9 + k];
  int e1 = rp[i + 1];
  for (int e = rp[i]; e < e1; ++e) {
    int nb = col[e];
    #pragma unroll
    for (int k = 0; k < 9; ++k) a[k] += x[(size_t)nb * 9 + k];
  }
  #pragma unroll
  for (int k = 0; k < 9; ++k) u[(size_t)i * 16 + k] = a[k];
}

// ---------------- layer 1 GEMM (K=9, fp32): h(bf16) = u @ W1 + b1, + column stats ----------------
__global__ __launch_bounds__(256) void k_l1gemm(const float* __restrict__ u,
    const float* __restrict__ W1, const float* __restrict__ b1,
    unsigned short* __restrict__ h, float* __restrict__ s_sum, float* __restrict__ s_sq) {
  __shared__ float Ws[9][256];
  int t = threadIdx.x;
  #pragma unroll
  for (int k = 0; k < 9; ++k) Ws[k][t] = W1[k * 256 + t];
  float bj = b1[t];
  __syncthreads();
  int r0 = blockIdx.x * 128;
  int r1 = min(r0 + 128, NN);
  float sum = 0.f, sq = 0.f;
  for (int r = r0; r < r1; ++r) {
    float acc = bj;
    #pragma unroll
    for (int k = 0; k < 9; ++k) acc = fmaf(u[(size_t)r * 16 + k], Ws[k][t], acc);
    h[(size_t)r * 256 + t] = f2bf(acc);
    sum += acc; sq += acc * acc;
  }
  atomicAdd(&s_sum[t], sum);
  atomicAdd(&s_sq[t], sq);
}

// ---------------- BN finalize; re-zeroes stats for the next layer ----------------
__global__ void k_finalize(float* __restrict__ s_sum, float* __restrict__ s_sq,
                           const float* __restrict__ g, const float* __restrict__ be,
                           float* __restrict__ scale, float* __restrict__ shift) {
  int j = threadIdx.x;
  float m = s_sum[j] / (float)NN;
  float v = s_sq[j] / (float)NN - m * m;
  v = fmaxf(v, 0.f);
  float sc = rsqrtf(v + BN_EPS) * g[j];
  scale[j] = sc;
  shift[j] = be[j] - m * sc;
  s_sum[j] = 0.f;
  s_sq[j] = 0.f;
}

// ---------------- BN apply + relu, bf16 -> bf16 ----------------
__global__ __launch_bounds__(256) void k_bnapply(const unsigned short* __restrict__ h,
    const float* __restrict__ scale, const float* __restrict__ shift, unsigned short* __restrict__ a) {
  __shared__ float sc[256], sh[256];
  sc[threadIdx.x] = scale[threadIdx.x];
  sh[threadIdx.x] = shift[threadIdx.x];
  __syncthreads();
  const int total = NN * 32;  // chunks of 8 bf16
  for (int idx = blockIdx.x * 256 + threadIdx.x; idx < total; idx += gridDim.x * 256) {
    int c0 = (idx & 31) * 8;
    ushort8 v = *(const ushort8*)(h + (size_t)idx * 8);
    ushort8 o;
    #pragma unroll
    for (int j = 0; j < 8; ++j) {
      float f = bf2f(v[j]);
      f = fmaxf(fmaf(f, sc[c0 + j], sh[c0 + j]), 0.f);
      o[j] = f2bf(f);
    }
    *(ushort8*)(a + (size_t)idx * 8) = o;
  }
}

// ---------------- aggregation F=256 bf16: u = f[i] + sum_nb f[nb] ----------------
__global__ __launch_bounds__(256) void k_agg256(const unsigned short* __restrict__ f,
    const int* __restrict__ rp, const int* __restrict__ col, unsigned short* __restrict__ u) {
  int half = threadIdx.x >> 5;
  int lane32 = threadIdx.x & 31;
  int node = blockIdx.x * 8 + threadIdx.y * 2 + half;
  if (node >= NN) return;
  float acc[8];
  ushort8 v = *(const ushort8*)(f + (size_t)node * HD + lane32 * 8);
  #pragma unroll
  for (int j = 0; j < 8; ++j) acc[j] = bf2f(v[j]);
  int e0 = rp[node], e1 = rp[node + 1];
  int e = e0;
  for (; e + 1 < e1; e += 2) {
    int nb0 = col[e], nb1 = col[e + 1];
    ushort8 w0 = *(const ushort8*)(f + (size_t)nb0 * HD + lane32 * 8);
    ushort8 w1 = *(const ushort8*)(f + (size_t)nb1 * HD + lane32 * 8);
    #pragma unroll
    for (int j = 0; j < 8; ++j) acc[j] += bf2f(w0[j]) + bf2f(w1[j]);
  }
  if (e < e1) {
    int nb = col[e];
    ushort8 w = *(const ushort8*)(f + (size_t)nb * HD + lane32 * 8);
    #pragma unroll
    for (int j = 0; j < 8; ++j) acc[j] += bf2f(w[j]);
  }
  ushort8 o;
  #pragma unroll
  for (int j = 0; j < 8; ++j) o[j] = f2bf(acc[j]);
  *(ushort8*)(u + (size_t)node * HD + lane32 * 8) = o;
}

// ---------------- MFMA bf16 GEMM: C[NN,256] = A[NN,256] @ B[256,256] + bias ----------------
// 64-row blocks, 4 waves each own a 64-col quadrant. B streamed from L2 per K-step
// (double-buffered fragments, ~140 VGPR -> 3 blocks/CU). A double-buffered in LDS via
// global_load_lds with XOR granule swizzle (LDS[row][g] = global[row][g^(row&7)]).
template<bool STATS, bool RELU, bool OUTSUM, bool WRITE>
__global__ __launch_bounds__(256, 3) void k_mfma_gemm(
    const unsigned short* __restrict__ A, const unsigned short* __restrict__ Bp,
    const float* __restrict__ bias, unsigned short* __restrict__ C,
    float* __restrict__ s_sum, float* __restrict__ s_sq, float* __restrict__ out)
{
  __shared__ unsigned short As[2][64 * 64];  // 16 KB
  const int t = threadIdx.x;
  const int w = t >> 6;
  const int lane = t & 63;
  const int brow = blockIdx.x * 64;
  const bf16x8* Bf = (const bf16x8*)Bp;

  f32x4 zero; zero.x = zero.y = zero.z = zero.w = 0.f;
  f32x4 acc[4][4];
  #pragma unroll
  for (int i = 0; i < 4; ++i)
    #pragma unroll
    for (int j = 0; j < 4; ++j) acc[i][j] = zero;

  auto stage = [&](int buf, int kt) {
    #pragma unroll
    for (int hh = 0; hh < 2; ++hh) {
      int r0 = w * 16 + hh * 8;
      int row = r0 + (lane >> 3);
      int gp = (lane & 7) ^ (row & 7);
      int grow = brow + row; if (grow >= NN) grow = NN - 1;
      const unsigned short* gptr = A + (size_t)grow * HD + kt + gp * 8;
      __builtin_amdgcn_global_load_lds(
          (const __attribute__((address_space(1))) void*)gptr,
          (__attribute__((address_space(3))) void*)&As[buf][r0 * 64], 16, 0, 0);
    }
  };

  bf16x8 bcur[4], bnxt[4];
  #pragma unroll
  for (int ntl = 0; ntl < 4; ++ntl)
    bcur[ntl] = Bf[(size_t)((w * 4 + ntl) * 8 + 0) * 64 + lane];
  stage(0, 0);
  __syncthreads();

  #pragma unroll
  for (int step = 0; step < 8; ++step) {
    const int tt = step >> 1, s = step & 1;
    if (s == 0 && tt < 3) stage((tt + 1) & 1, (tt + 1) * 64);
    if (step < 7) {
      #pragma unroll
      for (int ntl = 0; ntl < 4; ++ntl)
        bnxt[ntl] = Bf[(size_t)((w * 4 + ntl) * 8 + step + 1) * 64 + lane];
    }
    bf16x8 afr[4];
    #pragma unroll
    for (int mt = 0; mt < 4; ++mt) {
      int row = mt * 16 + (lane & 15);
      int g = s * 4 + (lane >> 4);
      int gp = g ^ (row & 7);
      afr[mt] = *(const bf16x8*)&As[tt & 1][row * 64 + gp * 8];
    }
    #pragma unroll
    for (int mt = 0; mt < 4; ++mt)
      #pragma unroll
      for (int ntl = 0; ntl < 4; ++ntl)
        acc[mt][ntl] = __builtin_amdgcn_mfma_f32_16x16x32_bf16(
            afr[mt], bcur[ntl], acc[mt][ntl], 0, 0, 0);
    #pragma unroll
    for (int ntl = 0; ntl < 4; ++ntl) bcur[ntl] = bnxt[ntl];
    if (s == 1 && tt < 3) __syncthreads();
  }

  // epilogue
  const int cl = lane & 15;
  const int rq = (lane >> 4) * 4;
  #pragma unroll
  for (int ntl = 0; ntl < 4; ++ntl) {
    const int cgl = w * 64 + ntl * 16 + cl;
    const float bv = bias[cgl];
    float s = 0.f, q = 0.f;
    #pragma unroll
    for (int mt = 0; mt < 4; ++mt) {
      #pragma unroll
      for (int i = 0; i < 4; ++i) {
        float v = acc[mt][ntl][i] + bv;
        if (RELU) v = fmaxf(v, 0.f);
        int grow = brow + mt * 16 + rq + i;
        bool valid = grow < NN;
        if (WRITE && valid) C[(size_t)grow * HD + cgl] = f2bf(v);
        if ((STATS || OUTSUM) && valid) { s += v; if (STATS) q += v * v; }
      }
    }
    if (STATS || OUTSUM) {
      s += __shfl_xor(s, 16); s += __shfl_xor(s, 32);
      if (STATS) { q += __shfl_xor(q, 16); q += __shfl_xor(q, 32); }
      if (lane < 16) {
        if (STATS) { atomicAdd(&s_sum[cgl], s); atomicAdd(&s_sq[cgl], q); }
        if (OUTSUM) atomicAdd(&out[cgl], s);
      }
    }
  }
}

extern "C" void kernel_launch(void* const* d_in, const int* in_sizes, int n_in,
                              void* d_out, int out_size, void* d_ws, size_t ws_size,
                              hipStream_t stream) {
  (void)in_sizes; (void)n_in; (void)out_size; (void)ws_size;
  const float* x  = (const float*)d_in[0];
  const int*  ei  = (const int*)d_in[1];
  const int*  src = ei;
  const int*  dst = ei + NE;
  const float* W1[3] = {(const float*)d_in[2],  (const float*)d_in[8],  (const float*)d_in[14]};
  const float* b1[3] = {(const float*)d_in[3],  (const float*)d_in[9],  (const float*)d_in[15]};
  const float* g_[3] = {(const float*)d_in[4],  (const float*)d_in[10], (const float*)d_in[16]};
  const float* be[3] = {(const float*)d_in[5],  (const float*)d_in[11], (const float*)d_in[17]};
  const float* W2[3] = {(const float*)d_in[6],  (const float*)d_in[12], (const float*)d_in[18]};
  const float* b2[3] = {(const float*)d_in[7],  (const float*)d_in[13], (const float*)d_in[19]};

  char* ws = (char*)d_ws;
  size_t o = 0;
  auto alloc = [&](size_t bytes) -> void* {
    void* p = ws + o;
    o += (bytes + 255) & ~(size_t)255;
    return p;
  };
  int*   rp     = (int*)alloc((size_t)(NN + 1) * 4);
  int*   cursor = (int*)alloc((size_t)NN * 4);
  int*   col    = (int*)alloc((size_t)NE * 4);
  int*   bsum   = (int*)alloc(64 * 4);
  float* u9     = (float*)alloc((size_t)NN * 16 * 4);
  unsigned short* ubf = (unsigned short*)alloc((size_t)NN * HD * 2);
  unsigned short* hbf = (unsigned short*)alloc((size_t)NN * HD * 2);
  unsigned short* abf = (unsigned short*)alloc((size_t)NN * HD * 2);
  unsigned short* fbf = (unsigned short*)alloc((size_t)NN * HD * 2);
  unsigned short* Wp  = (unsigned short*)alloc((size_t)5 * HD * HD * 2);
  float* s_sum  = (float*)alloc(HD * 4);
  float* s_sq   = (float*)alloc(HD * 4);
  float* scale  = (float*)alloc(HD * 4);
  float* shift  = (float*)alloc(HD * 4);
  float* out    = (float*)d_out;

  const int SCB = (NN + 1023) / 1024;  // 49

  k_zero<<<SCB, 1024, 0, stream>>>(cursor, s_sum, s_sq, out);
  k_count<<<(NE + 255) / 256, 256, 0, stream>>>(dst, cursor);
  k_scan_a<<<SCB, 1024, 0, stream>>>(cursor, rp, bsum);
  k_scan_b<<<SCB, 1024, 0, stream>>>(bsum, rp, cursor);
  k_fill<<<(NE + 255) / 256, 256, 0, stream>>>(src, dst, cursor, col);
  k_prepW5<<<dim3(256, 5), 256, 0, stream>>>(W2[0], W1[1], W2[1], W1[2], W2[2], Wp);

  unsigned short* WpA[5];
  for (int i = 0; i < 5; ++i) WpA[i] = Wp + (size_t)i * HD * HD;

  const int gemmGrid = (NN + 63) / 64;
  dim3 aGrid((NN + 7) / 8);
  dim3 aBlk(64, 4);

  // ---- layer 1 ----
  k_agg9<<<(NN + 255) / 256, 256, 0, stream>>>(x, rp, col, u9);
  k_l1gemm<<<(NN + 127) / 128, 256, 0, stream>>>(u9, W1[0], b1[0], hbf, s_sum, s_sq);
  k_finalize<<<1, HD, 0, stream>>>(s_sum, s_sq, g_[0], be[0], scale, shift);
  k_bnapply<<<2048, 256, 0, stream>>>(hbf, scale, shift, abf);
  k_mfma_gemm<false, true, false, true><<<gemmGrid, 256, 0, stream>>>(
      abf, WpA[0], b2[0], fbf, nullptr, nullptr, nullptr);

  // ---- layer 2 ----
  k_agg256<<<aGrid, aBlk, 0, stream>>>(fbf, rp, col, ubf);
  k_mfma_gemm<true, false, false, true><<<gemmGrid, 256, 0, stream>>>(
      ubf, WpA[1], b1[1], hbf, s_sum, s_sq, nullptr);
  k_finalize<<<1, HD, 0, stream>>>(s_sum, s_sq, g_[1], be[1], scale, shift);
  k_bnapply<<<2048, 256, 0, stream>>>(hbf, scale, shift, abf);
  k_mfma_gemm<false, true, false, true><<<gemmGrid, 256, 0, stream>>>(
      abf, WpA[2], b2[1], fbf, nullptr, nullptr, nullptr);

  // ---- layer 3 ----
  k_agg256<<<aGrid, aBlk, 0, stream>>>(fbf, rp, col, ubf);
  k_mfma_gemm<true, false, false, true><<<gemmGrid, 256, 0, stream>>>(
      ubf, WpA[3], b1[2], hbf, s_sum, s_sq, nullptr);
  k_finalize<<<1, HD, 0, stream>>>(s_sum, s_sq, g_[2], be[2], scale, shift);
  k_bnapply<<<2048, 256, 0, stream>>>(hbf, scale, shift, abf);
  k_mfma_gemm<false, true, true, false><<<gemmGrid, 256, 0, stream>>>(
      abf, WpA[4], b2[2], nullptr, nullptr, nullptr, out);
}